// Round 16
// baseline (33.947 us; speedup 1.0000x reference)
//
#include <hip/hip_runtime.h>

// B=16, S=256, IN=128, OUT=128, HID=512
// y[b,o] = sum_{k=h*128+i} M[b,k]*W2f[k*128+o] + sum_i sx[b,i]*b2[i*128+o]
//   M[b,h,i] = sum_s h[b,s,h]*x[b,s,i],  h = relu(x@W1+b1);  out = y@Wfc + bfc
// 3 kernels: AB (GEMM1+GEMM2 fused MFMA), C (kpar-split W2 stream, skewed Ms),
//            D (final reduce, 1024 thr).

typedef __attribute__((ext_vector_type(8))) short     s16x8;
typedef __attribute__((ext_vector_type(8))) unsigned short u16x8;
typedef __attribute__((ext_vector_type(4))) float     f32x4;

__device__ __forceinline__ unsigned short f2bf(float f) {
    union { float f; unsigned int u; } v; v.f = f;
    unsigned int r = v.u + 0x7FFFu + ((v.u >> 16) & 1u);   // RNE
    return (unsigned short)(r >> 16);
}
__device__ __forceinline__ float bf2f(unsigned short u) {
    union { unsigned int u; float f; } v; v.u = ((unsigned int)u) << 16;
    return v.f;
}

// ws float offsets
#define OFF_MP   0          // Mp   f32 [2][16][65536] -> 2097152 f
#define OFF_PART 2097152    // part f32 [512][16][128] -> 1048576 f
#define OFF_SXP  3145728    // sxp  f32 [4][16][128]   -> 8192 f

// ---------- Stage AB (R13-proven): GEMM1 (x@W1 -> h in LDS) + GEMM2 (h^T@x -> Mp) ----------
__global__ __launch_bounds__(256) void k_AB(const float* __restrict__ x,
        const float* __restrict__ W1, const float* __restrict__ b1,
        float* __restrict__ Mp, float* __restrict__ sxp) {
    __shared__ __align__(16) unsigned char smem[87296];
    auto Ws  = (unsigned short (*)[136])(smem);            // [64][136] hid x i
    auto xA  = (unsigned short (*)[136])(smem + 17408);    // [128][136] s x i
    auto xTl = (unsigned short (*)[136])(smem + 52224);    // [128][136] i x s
    auto Wt  = (float (*)[33])(smem + 52224);              // f32 staging (alias xTl)
    float* b1s = (float*)(smem + 87040);
    auto hts = (unsigned short (*)[136])(smem);            // [64][136] alias Ws

    const int tid = threadIdx.x;
    const int b  = blockIdx.x >> 4;
    const int hb = (blockIdx.x >> 1) & 7;
    const int sh = blockIdx.x & 1;

    {
        const int r = tid >> 1, q = tid & 1;
        const float* xrow = &x[(size_t)(b * 256 + sh * 128 + r) * 128 + q * 64];
        #pragma unroll
        for (int m = 0; m < 8; ++m) {
            const float4 v0 = *(const float4*)&xrow[m * 8];
            const float4 v1 = *(const float4*)&xrow[m * 8 + 4];
            unsigned short t8[8] __attribute__((aligned(16))) = {
                f2bf(v0.x), f2bf(v0.y), f2bf(v0.z), f2bf(v0.w),
                f2bf(v1.x), f2bf(v1.y), f2bf(v1.z), f2bf(v1.w)};
            *(u16x8*)&xA[r][q * 64 + m * 8] = *(u16x8*)t8;
        }
        if (tid < 64) b1s[tid] = b1[hb * 64 + tid];
    }
    for (int hq = 0; hq < 2; ++hq) {
        __syncthreads();
        #pragma unroll
        for (int p = 0; p < 16; ++p) {
            const int flat = p * 256 + tid;
            const int i = flat >> 5, hc = flat & 31;
            Wt[i][hc] = W1[(size_t)i * 512 + hb * 64 + hq * 32 + hc];
        }
        __syncthreads();
        {
            const int h2 = tid >> 3, pt = tid & 7;
            unsigned short t16[16] __attribute__((aligned(16)));
            #pragma unroll
            for (int m = 0; m < 16; ++m)
                t16[m] = f2bf(Wt[pt * 16 + m][h2]);
            *(u16x8*)&Ws[hq * 32 + h2][pt * 16]     = *(u16x8*)&t16[0];
            *(u16x8*)&Ws[hq * 32 + h2][pt * 16 + 8] = *(u16x8*)&t16[8];
        }
    }
    __syncthreads();

    const int w = tid >> 6, lane = tid & 63;
    const int wr = w >> 1, wc = w & 1;
    const int l15 = lane & 15, kl = lane >> 4;
    f32x4 zero = {0.f, 0.f, 0.f, 0.f};

    // GEMM1: C[tok 128][hid 64]; wave tile 64x32
    f32x4 acc[4][2];
    #pragma unroll
    for (int i = 0; i < 4; ++i)
        #pragma unroll
        for (int j = 0; j < 2; ++j) acc[i][j] = zero;
    #pragma unroll
    for (int ks = 0; ks < 4; ++ks) {
        s16x8 a[4], bb[2];
        #pragma unroll
        for (int f = 0; f < 4; ++f)
            a[f] = *(const s16x8*)&xA[wr * 64 + f * 16 + l15][ks * 32 + kl * 8];
        #pragma unroll
        for (int f = 0; f < 2; ++f)
            bb[f] = *(const s16x8*)&Ws[wc * 32 + f * 16 + l15][ks * 32 + kl * 8];
        #pragma unroll
        for (int fr = 0; fr < 4; ++fr)
            #pragma unroll
            for (int fc = 0; fc < 2; ++fc)
                acc[fr][fc] = __builtin_amdgcn_mfma_f32_16x16x32_bf16(a[fr], bb[fc], acc[fr][fc], 0, 0, 0);
    }
    __syncthreads();

    // build xTl (transpose of xA) + sxp partials (hb==0); Wt region is dead
    {
        const int i = tid >> 1, q = tid & 1;
        float sacc = 0.f;
        unsigned short t64[64] __attribute__((aligned(16)));
        #pragma unroll
        for (int m = 0; m < 64; ++m) {
            const unsigned short u = xA[q * 64 + m][i];
            sacc += bf2f(u);
            t64[m] = u;
        }
        #pragma unroll
        for (int v = 0; v < 8; ++v)
            *(u16x8*)&xTl[i][q * 64 + v * 8] = *(u16x8*)&t64[v * 8];
        if (hb == 0)
            sxp[(size_t)((sh * 2 + q) * 16 + b) * 128 + i] = sacc;
    }
    __syncthreads();

    // write hts (relu, bf16, [hid 64][tok 128]) into Ws region
    #pragma unroll
    for (int fr = 0; fr < 4; ++fr)
        #pragma unroll
        for (int fc = 0; fc < 2; ++fc)
            #pragma unroll
            for (int j = 0; j < 4; ++j) {
                const int tok = wr * 64 + fr * 16 + kl * 4 + j;
                const int hid = wc * 32 + fc * 16 + l15;
                const float v = acc[fr][fc][j] + b1s[hid];
                hts[hid][tok] = f2bf(v > 0.f ? v : 0.f);
            }
    __syncthreads();

    // GEMM2: Mp[sh][b][hb*64+h][i] = hts @ xTl; wave tile 32x64
    f32x4 acc2[2][4];
    #pragma unroll
    for (int i = 0; i < 2; ++i)
        #pragma unroll
        for (int j = 0; j < 4; ++j) acc2[i][j] = zero;
    #pragma unroll
    for (int ks = 0; ks < 4; ++ks) {
        s16x8 a2[2], b2f[4];
        #pragma unroll
        for (int f = 0; f < 2; ++f)
            a2[f] = *(const s16x8*)&hts[wr * 32 + f * 16 + l15][ks * 32 + kl * 8];
        #pragma unroll
        for (int f = 0; f < 4; ++f)
            b2f[f] = *(const s16x8*)&xTl[wc * 64 + f * 16 + l15][ks * 32 + kl * 8];
        #pragma unroll
        for (int fr = 0; fr < 2; ++fr)
            #pragma unroll
            for (int fc = 0; fc < 4; ++fc)
                acc2[fr][fc] = __builtin_amdgcn_mfma_f32_16x16x32_bf16(a2[fr], b2f[fc], acc2[fr][fc], 0, 0, 0);
    }
    const size_t mpbase = (size_t)(sh * 16 + b) * 65536;
    #pragma unroll
    for (int fr = 0; fr < 2; ++fr)
        #pragma unroll
        for (int fc = 0; fc < 4; ++fc)
            #pragma unroll
            for (int j = 0; j < 4; ++j) {
                const int h = hb * 64 + wr * 32 + fr * 16 + kl * 4 + j;
                const int i = wc * 64 + fc * 16 + l15;
                Mp[mpbase + (size_t)h * 128 + i] = acc2[fr][fc][j];
            }
}

// ---------- Stage C: y-partials = Ms @ W2-rows, K=128/block, 512 blocks ----------
// lane = kpar*16+og: kpar splits K 4-way across lanes, og*8 covers o (2 float4).
// Ms skewed [16][144] (36*kpar+i) -> the 4 kpar broadcast reads hit disjoint banks.
// Per thread: 32 k, 32 ds_read_b128 total, 8-deep W2 float4 staging.
__global__ __launch_bounds__(256) void k_C(const float* __restrict__ Mp,
        const float* __restrict__ W2, float* __restrict__ part) {
    __shared__ float Msl[16][144];
    const int tid = threadIdx.x;
    const int p = blockIdx.x;
    const int k0 = p * 128;
    #pragma unroll
    for (int r = 0; r < 8; ++r) {
        const int flat = r * 256 + tid;
        const int b = flat >> 7, kk = flat & 127;
        Msl[b][36 * (kk >> 5) + (kk & 31)] =
            Mp[(size_t)b * 65536 + k0 + kk] + Mp[(size_t)(16 + b) * 65536 + k0 + kk];
    }
    __syncthreads();
    const int lane = tid & 63, wb = tid >> 6;     // warp -> b-rows wb*4..+3
    const int kpar = lane >> 4, og = lane & 15;
    const int o8 = og * 8;
    float acc[4][8] = {};
    for (int ib = 0; ib < 8; ++ib) {
        float4 wst[8];
        #pragma unroll
        for (int j = 0; j < 4; ++j) {
            const size_t row = (size_t)(k0 + kpar * 32 + ib * 4 + j) * 128;
            wst[j * 2]     = *(const float4*)&W2[row + o8];
            wst[j * 2 + 1] = *(const float4*)&W2[row + o8 + 4];
        }
        float4 mv[4];
        #pragma unroll
        for (int bb = 0; bb < 4; ++bb)
            mv[bb] = *(const float4*)&Msl[wb * 4 + bb][36 * kpar + ib * 4];
        #pragma unroll
        for (int j = 0; j < 4; ++j) {
            const float4 w0 = wst[j * 2], w1 = wst[j * 2 + 1];
            #pragma unroll
            for (int bb = 0; bb < 4; ++bb) {
                const float m = ((const float*)&mv[bb])[j];
                acc[bb][0] += m * w0.x; acc[bb][1] += m * w0.y;
                acc[bb][2] += m * w0.z; acc[bb][3] += m * w0.w;
                acc[bb][4] += m * w1.x; acc[bb][5] += m * w1.y;
                acc[bb][6] += m * w1.z; acc[bb][7] += m * w1.w;
            }
        }
    }
    // reduce across kpar (lanes ^16, ^32)
    #pragma unroll
    for (int bb = 0; bb < 4; ++bb)
        #pragma unroll
        for (int o = 0; o < 8; ++o) {
            acc[bb][o] += __shfl_xor(acc[bb][o], 16);
            acc[bb][o] += __shfl_xor(acc[bb][o], 32);
        }
    if (kpar == 0) {
        #pragma unroll
        for (int bb = 0; bb < 4; ++bb) {
            float4 v0 = {acc[bb][0], acc[bb][1], acc[bb][2], acc[bb][3]};
            float4 v1 = {acc[bb][4], acc[bb][5], acc[bb][6], acc[bb][7]};
            float* dst = &part[(size_t)(p * 16 + wb * 4 + bb) * 128 + o8];
            *(float4*)dst = v0;
            *(float4*)(dst + 4) = v1;
        }
    }
}

// ---------- Stage D: reduce 512 partials + b2 term + Wfc + bfc (1024 thr, 8 groups) ----------
__global__ __launch_bounds__(1024) void k_D(const float* __restrict__ part,
        const float* __restrict__ sxp, const float* __restrict__ b2,
        const float* __restrict__ Wfc, const float* __restrict__ bfc,
        float* __restrict__ out) {
    __shared__ float sh[8][128];
    __shared__ float sxs[128];
    __shared__ float ysum[128];
    __shared__ float ysh[128];
    const int b = blockIdx.x;
    const int t = threadIdx.x & 127;
    const int g = threadIdx.x >> 7;
    float y = 0.f;
    #pragma unroll 8
    for (int pp = g * 64; pp < g * 64 + 64; ++pp)
        y += part[(size_t)(pp * 16 + b) * 128 + t];
    sh[g][t] = y;
    __syncthreads();
    if (g == 0) {
        float yy = sh[0][t];
        #pragma unroll
        for (int j = 1; j < 8; ++j) yy += sh[j][t];
        ysum[t] = yy;
        sxs[t] = sxp[(size_t)(0 * 16 + b) * 128 + t] + sxp[(size_t)(1 * 16 + b) * 128 + t]
               + sxp[(size_t)(2 * 16 + b) * 128 + t] + sxp[(size_t)(3 * 16 + b) * 128 + t];
    }
    __syncthreads();
    float yb = 0.f;
    #pragma unroll
    for (int i = g * 16; i < g * 16 + 16; ++i)
        yb += sxs[i] * b2[i * 128 + t];
    sh[g][t] = yb;
    __syncthreads();
    if (g == 0) {
        float yy = ysum[t];
        #pragma unroll
        for (int j = 0; j < 8; ++j) yy += sh[j][t];
        ysh[t] = yy;
    }
    __syncthreads();
    float f = 0.f;
    #pragma unroll
    for (int oo = g * 16; oo < g * 16 + 16; ++oo)
        f += ysh[oo] * Wfc[oo * 128 + t];
    sh[g][t] = f;
    __syncthreads();
    if (g == 0) {
        float s = bfc[t];
        #pragma unroll
        for (int j = 0; j < 8; ++j) s += sh[j][t];
        out[b * 128 + t] = s;
    }
}

extern "C" void kernel_launch(void* const* d_in, const int* in_sizes, int n_in,
                              void* d_out, int out_size, void* d_ws, size_t ws_size,
                              hipStream_t stream) {
    const float* x   = (const float*)d_in[0];
    const float* W1  = (const float*)d_in[1];
    const float* b1  = (const float*)d_in[2];
    const float* W2  = (const float*)d_in[3];
    const float* b2  = (const float*)d_in[4];
    const float* Wfc = (const float*)d_in[5];
    const float* bfc = (const float*)d_in[6];
    float* ws  = (float*)d_ws;
    float* Mp   = ws + OFF_MP;
    float* part = ws + OFF_PART;
    float* sxp  = ws + OFF_SXP;
    float* out  = (float*)d_out;

    k_AB<<<256, 256, 0, stream>>>(x, W1, b1, Mp, sxp);
    k_C <<<512, 256, 0, stream>>>(Mp, W2, part);
    k_D <<<16, 1024, 0, stream>>>(part, sxp, b2, Wfc, bfc, out);
}

// Round 17
// 33.246 us; speedup vs baseline: 1.0211x; 1.0211x over previous
//
#include <hip/hip_runtime.h>

// B=16, S=256, IN=128, OUT=128, HID=512
// y[b,o] = sum_{k=h*128+i} M[b,k]*W2f[k*128+o] + sum_i sx[b,i]*b2[i*128+o]
//   M[b,h,i] = sum_s h[b,s,h]*x[b,s,i],  h = relu(x@W1+b1);  out = y@Wfc + bfc
// 3 kernels: AB (GEMM1+GEMM2 fused MFMA), C (K-across-warps: W2 read ONCE/block),
//            D (final reduce, 1024 thr).

typedef __attribute__((ext_vector_type(8))) short     s16x8;
typedef __attribute__((ext_vector_type(8))) unsigned short u16x8;
typedef __attribute__((ext_vector_type(4))) float     f32x4;

__device__ __forceinline__ unsigned short f2bf(float f) {
    union { float f; unsigned int u; } v; v.f = f;
    unsigned int r = v.u + 0x7FFFu + ((v.u >> 16) & 1u);   // RNE
    return (unsigned short)(r >> 16);
}
__device__ __forceinline__ float bf2f(unsigned short u) {
    union { unsigned int u; float f; } v; v.u = ((unsigned int)u) << 16;
    return v.f;
}

// ws float offsets
#define OFF_MP   0          // Mp   f32 [2][16][65536] -> 2097152 f
#define OFF_PART 2097152    // part f32 [512][16][128] -> 1048576 f
#define OFF_SXP  3145728    // sxp  f32 [4][16][128]   -> 8192 f

// ---------- Stage AB (R13-proven): GEMM1 (x@W1 -> h in LDS) + GEMM2 (h^T@x -> Mp) ----------
__global__ __launch_bounds__(256) void k_AB(const float* __restrict__ x,
        const float* __restrict__ W1, const float* __restrict__ b1,
        float* __restrict__ Mp, float* __restrict__ sxp) {
    __shared__ __align__(16) unsigned char smem[87296];
    auto Ws  = (unsigned short (*)[136])(smem);            // [64][136] hid x i
    auto xA  = (unsigned short (*)[136])(smem + 17408);    // [128][136] s x i
    auto xTl = (unsigned short (*)[136])(smem + 52224);    // [128][136] i x s
    auto Wt  = (float (*)[33])(smem + 52224);              // f32 staging (alias xTl)
    float* b1s = (float*)(smem + 87040);
    auto hts = (unsigned short (*)[136])(smem);            // [64][136] alias Ws

    const int tid = threadIdx.x;
    const int b  = blockIdx.x >> 4;
    const int hb = (blockIdx.x >> 1) & 7;
    const int sh = blockIdx.x & 1;

    {
        const int r = tid >> 1, q = tid & 1;
        const float* xrow = &x[(size_t)(b * 256 + sh * 128 + r) * 128 + q * 64];
        #pragma unroll
        for (int m = 0; m < 8; ++m) {
            const float4 v0 = *(const float4*)&xrow[m * 8];
            const float4 v1 = *(const float4*)&xrow[m * 8 + 4];
            unsigned short t8[8] __attribute__((aligned(16))) = {
                f2bf(v0.x), f2bf(v0.y), f2bf(v0.z), f2bf(v0.w),
                f2bf(v1.x), f2bf(v1.y), f2bf(v1.z), f2bf(v1.w)};
            *(u16x8*)&xA[r][q * 64 + m * 8] = *(u16x8*)t8;
        }
        if (tid < 64) b1s[tid] = b1[hb * 64 + tid];
    }
    for (int hq = 0; hq < 2; ++hq) {
        __syncthreads();
        #pragma unroll
        for (int p = 0; p < 16; ++p) {
            const int flat = p * 256 + tid;
            const int i = flat >> 5, hc = flat & 31;
            Wt[i][hc] = W1[(size_t)i * 512 + hb * 64 + hq * 32 + hc];
        }
        __syncthreads();
        {
            const int h2 = tid >> 3, pt = tid & 7;
            unsigned short t16[16] __attribute__((aligned(16)));
            #pragma unroll
            for (int m = 0; m < 16; ++m)
                t16[m] = f2bf(Wt[pt * 16 + m][h2]);
            *(u16x8*)&Ws[hq * 32 + h2][pt * 16]     = *(u16x8*)&t16[0];
            *(u16x8*)&Ws[hq * 32 + h2][pt * 16 + 8] = *(u16x8*)&t16[8];
        }
    }
    __syncthreads();

    const int w = tid >> 6, lane = tid & 63;
    const int wr = w >> 1, wc = w & 1;
    const int l15 = lane & 15, kl = lane >> 4;
    f32x4 zero = {0.f, 0.f, 0.f, 0.f};

    // GEMM1: C[tok 128][hid 64]; wave tile 64x32
    f32x4 acc[4][2];
    #pragma unroll
    for (int i = 0; i < 4; ++i)
        #pragma unroll
        for (int j = 0; j < 2; ++j) acc[i][j] = zero;
    #pragma unroll
    for (int ks = 0; ks < 4; ++ks) {
        s16x8 a[4], bb[2];
        #pragma unroll
        for (int f = 0; f < 4; ++f)
            a[f] = *(const s16x8*)&xA[wr * 64 + f * 16 + l15][ks * 32 + kl * 8];
        #pragma unroll
        for (int f = 0; f < 2; ++f)
            bb[f] = *(const s16x8*)&Ws[wc * 32 + f * 16 + l15][ks * 32 + kl * 8];
        #pragma unroll
        for (int fr = 0; fr < 4; ++fr)
            #pragma unroll
            for (int fc = 0; fc < 2; ++fc)
                acc[fr][fc] = __builtin_amdgcn_mfma_f32_16x16x32_bf16(a[fr], bb[fc], acc[fr][fc], 0, 0, 0);
    }
    __syncthreads();

    // build xTl (transpose of xA) + sxp partials (hb==0); Wt region is dead
    {
        const int i = tid >> 1, q = tid & 1;
        float sacc = 0.f;
        unsigned short t64[64] __attribute__((aligned(16)));
        #pragma unroll
        for (int m = 0; m < 64; ++m) {
            const unsigned short u = xA[q * 64 + m][i];
            sacc += bf2f(u);
            t64[m] = u;
        }
        #pragma unroll
        for (int v = 0; v < 8; ++v)
            *(u16x8*)&xTl[i][q * 64 + v * 8] = *(u16x8*)&t64[v * 8];
        if (hb == 0)
            sxp[(size_t)((sh * 2 + q) * 16 + b) * 128 + i] = sacc;
    }
    __syncthreads();

    // write hts (relu, bf16, [hid 64][tok 128]) into Ws region
    #pragma unroll
    for (int fr = 0; fr < 4; ++fr)
        #pragma unroll
        for (int fc = 0; fc < 2; ++fc)
            #pragma unroll
            for (int j = 0; j < 4; ++j) {
                const int tok = wr * 64 + fr * 16 + kl * 4 + j;
                const int hid = wc * 32 + fc * 16 + l15;
                const float v = acc[fr][fc][j] + b1s[hid];
                hts[hid][tok] = f2bf(v > 0.f ? v : 0.f);
            }
    __syncthreads();

    // GEMM2: Mp[sh][b][hb*64+h][i] = hts @ xTl; wave tile 32x64
    f32x4 acc2[2][4];
    #pragma unroll
    for (int i = 0; i < 2; ++i)
        #pragma unroll
        for (int j = 0; j < 4; ++j) acc2[i][j] = zero;
    #pragma unroll
    for (int ks = 0; ks < 4; ++ks) {
        s16x8 a2[2], b2f[4];
        #pragma unroll
        for (int f = 0; f < 2; ++f)
            a2[f] = *(const s16x8*)&hts[wr * 32 + f * 16 + l15][ks * 32 + kl * 8];
        #pragma unroll
        for (int f = 0; f < 4; ++f)
            b2f[f] = *(const s16x8*)&xTl[wc * 64 + f * 16 + l15][ks * 32 + kl * 8];
        #pragma unroll
        for (int fr = 0; fr < 2; ++fr)
            #pragma unroll
            for (int fc = 0; fc < 4; ++fc)
                acc2[fr][fc] = __builtin_amdgcn_mfma_f32_16x16x32_bf16(a2[fr], b2f[fc], acc2[fr][fc], 0, 0, 0);
    }
    const size_t mpbase = (size_t)(sh * 16 + b) * 65536;
    #pragma unroll
    for (int fr = 0; fr < 2; ++fr)
        #pragma unroll
        for (int fc = 0; fc < 4; ++fc)
            #pragma unroll
            for (int j = 0; j < 4; ++j) {
                const int h = hb * 64 + wr * 32 + fr * 16 + kl * 4 + j;
                const int i = wc * 64 + fc * 16 + l15;
                Mp[mpbase + (size_t)h * 128 + i] = acc2[fr][fc][j];
            }
}

// ---------- Stage C: y-partials = Ms @ W2-rows, K=128/block, 512 blocks ----------
// K split ACROSS warps: warp w owns k in [w*32, w*32+32) for ALL 16 b's ->
// each W2 row is read by exactly one warp (64 KB/block, no duplication).
// Cross-warp combine via red[4][16][128] in LDS.
__global__ __launch_bounds__(256) void k_C(const float* __restrict__ Mp,
        const float* __restrict__ W2, float* __restrict__ part) {
    __shared__ float Ms[16][128];
    __shared__ float red[4][16][128];
    const int tid = threadIdx.x;
    const int p = blockIdx.x;
    const int k0 = p * 128;
    #pragma unroll
    for (int r = 0; r < 8; ++r) {
        const int flat = r * 256 + tid;
        const int b = flat >> 7, kk = flat & 127;
        Ms[b][kk] = Mp[(size_t)b * 65536 + k0 + kk]
                  + Mp[(size_t)(16 + b) * 65536 + k0 + kk];
    }
    __syncthreads();
    const int lane = tid & 63, w = tid >> 6;
    const int o2 = lane * 2;
    float2 acc[16];
    #pragma unroll
    for (int b = 0; b < 16; ++b) acc[b] = {0.f, 0.f};
    #pragma unroll 2
    for (int jt = 0; jt < 8; ++jt) {
        float2 wst[4];
        #pragma unroll
        for (int j = 0; j < 4; ++j)
            wst[j] = *(const float2*)&W2[(size_t)(k0 + w * 32 + jt * 4 + j) * 128 + o2];
        #pragma unroll
        for (int b = 0; b < 16; ++b) {
            const float4 mv = *(const float4*)&Ms[b][w * 32 + jt * 4];
            acc[b].x += mv.x * wst[0].x + mv.y * wst[1].x + mv.z * wst[2].x + mv.w * wst[3].x;
            acc[b].y += mv.x * wst[0].y + mv.y * wst[1].y + mv.z * wst[2].y + mv.w * wst[3].y;
        }
    }
    #pragma unroll
    for (int b = 0; b < 16; ++b)
        *(float2*)&red[w][b][o2] = acc[b];
    __syncthreads();
    // 2048 outputs / 256 threads = 8 each; sum the 4 warp partials
    {
        const int b  = tid >> 4;
        const int o0 = (tid & 15) * 8;
        float v[8];
        #pragma unroll
        for (int j = 0; j < 8; ++j)
            v[j] = red[0][b][o0 + j] + red[1][b][o0 + j]
                 + red[2][b][o0 + j] + red[3][b][o0 + j];
        float* dst = &part[(size_t)(p * 16 + b) * 128 + o0];
        *(float4*)dst       = *(float4*)&v[0];
        *(float4*)(dst + 4) = *(float4*)&v[4];
    }
}

// ---------- Stage D: reduce 512 partials + b2 term + Wfc + bfc (1024 thr, 8 groups) ----------
__global__ __launch_bounds__(1024) void k_D(const float* __restrict__ part,
        const float* __restrict__ sxp, const float* __restrict__ b2,
        const float* __restrict__ Wfc, const float* __restrict__ bfc,
        float* __restrict__ out) {
    __shared__ float sh[8][128];
    __shared__ float sxs[128];
    __shared__ float ysum[128];
    __shared__ float ysh[128];
    const int b = blockIdx.x;
    const int t = threadIdx.x & 127;
    const int g = threadIdx.x >> 7;
    float y = 0.f;
    #pragma unroll 8
    for (int pp = g * 64; pp < g * 64 + 64; ++pp)
        y += part[(size_t)(pp * 16 + b) * 128 + t];
    sh[g][t] = y;
    __syncthreads();
    if (g == 0) {
        float yy = sh[0][t];
        #pragma unroll
        for (int j = 1; j < 8; ++j) yy += sh[j][t];
        ysum[t] = yy;
        sxs[t] = sxp[(size_t)(0 * 16 + b) * 128 + t] + sxp[(size_t)(1 * 16 + b) * 128 + t]
               + sxp[(size_t)(2 * 16 + b) * 128 + t] + sxp[(size_t)(3 * 16 + b) * 128 + t];
    }
    __syncthreads();
    float yb = 0.f;
    #pragma unroll
    for (int i = g * 16; i < g * 16 + 16; ++i)
        yb += sxs[i] * b2[i * 128 + t];
    sh[g][t] = yb;
    __syncthreads();
    if (g == 0) {
        float yy = ysum[t];
        #pragma unroll
        for (int j = 0; j < 8; ++j) yy += sh[j][t];
        ysh[t] = yy;
    }
    __syncthreads();
    float f = 0.f;
    #pragma unroll
    for (int oo = g * 16; oo < g * 16 + 16; ++oo)
        f += ysh[oo] * Wfc[oo * 128 + t];
    sh[g][t] = f;
    __syncthreads();
    if (g == 0) {
        float s = bfc[t];
        #pragma unroll
        for (int j = 0; j < 8; ++j) s += sh[j][t];
        out[b * 128 + t] = s;
    }
}

extern "C" void kernel_launch(void* const* d_in, const int* in_sizes, int n_in,
                              void* d_out, int out_size, void* d_ws, size_t ws_size,
                              hipStream_t stream) {
    const float* x   = (const float*)d_in[0];
    const float* W1  = (const float*)d_in[1];
    const float* b1  = (const float*)d_in[2];
    const float* W2  = (const float*)d_in[3];
    const float* b2  = (const float*)d_in[4];
    const float* Wfc = (const float*)d_in[5];
    const float* bfc = (const float*)d_in[6];
    float* ws  = (float*)d_ws;
    float* Mp   = ws + OFF_MP;
    float* part = ws + OFF_PART;
    float* sxp  = ws + OFF_SXP;
    float* out  = (float*)d_out;

    k_AB<<<256, 256, 0, stream>>>(x, W1, b1, Mp, sxp);
    k_C <<<512, 256, 0, stream>>>(Mp, W2, part);
    k_D <<<16, 1024, 0, stream>>>(part, sxp, b2, Wfc, bfc, out);
}